// Round 1
// baseline (1387.427 us; speedup 1.0000x reference)
//
#include <hip/hip_runtime.h>
#include <stdint.h>

// BitLinear on MI355X: per-token int8 activation quant + per-tensor ternary
// weight quant + exact int8 MFMA GEMM (m97-style 128x128 tile structure).
//
// y[m,n] = (rowscale[m] * mw) * sum_k qx[m,k] * tw[n,k]
//   qx int8 (per-token absmax 127), tw in {-1,0,1}, mw = clip(mean|w|,EPS)
//   rowscale[m] = clip(max|x[m,:]|,EPS)/127

typedef int v4i __attribute__((ext_vector_type(4)));

#define QEPS 1e-5f

#define M_DIM 8192
#define N_DIM 16384
#define K_DIM 4096

#define BM 128
#define BN 128
#define BK 64

// ---------------- Kernel 1: sum of |w| (double accumulate) ----------------
__global__ void wabs_sum(const float* __restrict__ w, double* __restrict__ acc,
                         int n4) {
    int idx = blockIdx.x * blockDim.x + threadIdx.x;
    int stride = gridDim.x * blockDim.x;
    const float4* w4 = (const float4*)w;
    double s = 0.0;
    for (int i = idx; i < n4; i += stride) {
        float4 v = w4[i];
        s += (double)(fabsf(v.x) + fabsf(v.y) + fabsf(v.z) + fabsf(v.w));
    }
    // wave64 reduce
    #pragma unroll
    for (int off = 32; off > 0; off >>= 1)
        s += __shfl_down(s, off, 64);
    __shared__ double sm[4];
    int lane = threadIdx.x & 63, wv = threadIdx.x >> 6;
    if (lane == 0) sm[wv] = s;
    __syncthreads();
    if (threadIdx.x == 0) {
        atomicAdd(acc, sm[0] + sm[1] + sm[2] + sm[3]);
    }
}

// ---------------- Kernel 2: ternary weight quant ----------------
__device__ __forceinline__ int tq1(float v, float s) {
    float q = rintf(v * s);
    q = fminf(fmaxf(q, -1.0f), 1.0f);
    return (int)q;
}

__global__ void wquant(const float* __restrict__ w, int8_t* __restrict__ tw,
                       const double* __restrict__ acc, double inv_cnt, int n4) {
    double mean = (*acc) * inv_cnt;
    float mclip = (float)fmax(mean, (double)QEPS);
    float sw = 1.0f / mclip;
    int idx = blockIdx.x * blockDim.x + threadIdx.x;
    int stride = gridDim.x * blockDim.x;
    const float4* w4 = (const float4*)w;
    uint32_t* out = (uint32_t*)tw;
    for (int i = idx; i < n4; i += stride) {
        float4 v = w4[i];
        uint32_t a = (uint32_t)(tq1(v.x, sw) & 0xff);
        uint32_t b = (uint32_t)(tq1(v.y, sw) & 0xff);
        uint32_t c = (uint32_t)(tq1(v.z, sw) & 0xff);
        uint32_t d = (uint32_t)(tq1(v.w, sw) & 0xff);
        out[i] = a | (b << 8) | (c << 16) | (d << 24);
    }
}

// ---------------- Kernel 3: per-token int8 activation quant ----------------
__device__ __forceinline__ int q8(float v, float s) {
    float q = rintf(v * s);
    q = fminf(fmaxf(q, -128.0f), 127.0f);
    return (int)q;
}

__global__ void xquant(const float* __restrict__ x, int8_t* __restrict__ qx,
                       float* __restrict__ rowscale) {
    int row = blockIdx.x;
    int t = threadIdx.x;
    const float4* xr = (const float4*)(x + (size_t)row * K_DIM);
    float4 v[4];
    float m = 0.0f;
    #pragma unroll
    for (int i = 0; i < 4; i++) {
        v[i] = xr[t + i * 256];
        m = fmaxf(m, fmaxf(fmaxf(fabsf(v[i].x), fabsf(v[i].y)),
                           fmaxf(fabsf(v[i].z), fabsf(v[i].w))));
    }
    #pragma unroll
    for (int off = 32; off > 0; off >>= 1)
        m = fmaxf(m, __shfl_down(m, off, 64));
    __shared__ float sm[4];
    int lane = t & 63, wv = t >> 6;
    if (lane == 0) sm[wv] = m;
    __syncthreads();
    m = fmaxf(fmaxf(sm[0], sm[1]), fmaxf(sm[2], sm[3]));
    float mc = fmaxf(m, QEPS);
    float scale = 127.0f / mc;
    if (t == 0) rowscale[row] = mc * (1.0f / 127.0f);
    uint32_t* qr = (uint32_t*)(qx + (size_t)row * K_DIM);
    #pragma unroll
    for (int i = 0; i < 4; i++) {
        uint32_t a = (uint32_t)(q8(v[i].x, scale) & 0xff);
        uint32_t b = (uint32_t)(q8(v[i].y, scale) & 0xff);
        uint32_t c = (uint32_t)(q8(v[i].z, scale) & 0xff);
        uint32_t d = (uint32_t)(q8(v[i].w, scale) & 0xff);
        qr[t + i * 256] = a | (b << 8) | (c << 16) | (d << 24);
    }
}

// ---------------- Kernel 4: int8 MFMA GEMM (m97 structure) ----------------
__device__ __forceinline__ void async_copy16(const void* g, void* l) {
    __builtin_amdgcn_global_load_lds(
        (__attribute__((address_space(1))) void*)g,
        (__attribute__((address_space(3))) void*)l, 16, 0, 0);
}

__global__ __launch_bounds__(256, 2)
void gemm_i8(const int8_t* __restrict__ A,   // [M][K] int8
             const int8_t* __restrict__ B,   // [N][K] ternary int8
             const float* __restrict__ rowscale,
             const double* __restrict__ macc, double inv_cnt,
             float* __restrict__ C) {
    __shared__ int8_t As[BM * BK];  // 8 KB, 64 B per row, no padding
    __shared__ int8_t Bs[BN * BK];  // 8 KB

    const int tid = threadIdx.x;
    const int wave = tid >> 6;
    const int lane = tid & 63;
    const int bm = blockIdx.y * BM;
    const int bn = blockIdx.x * BN;
    const int wm = (wave & 1) << 6;   // wave's 64-row block within tile
    const int wn = (wave >> 1) << 6;  // wave's 64-col block within tile

    v4i acc[4][4] = {};  // 64 AGPRs of int32

    // Staging: tile = 8192 B = 512 chunks of 16 B; chunk c -> LDS offset c*16,
    // global row c/4, k-offset (c%4)*16.  Wave w issue i covers chunks
    // [i*256 + w*64, +64) with HW placing lane l at base + l*16.
    const int cbase = wave * 64 + lane;
    const int8_t* Abase = A + (size_t)bm * K_DIM;
    const int8_t* Bbase = B + (size_t)bn * K_DIM;

    const int fr = lane & 15;          // fragment row (A-m / B-n)
    const int kq = (lane >> 4) * 16;   // fragment k offset (16 contiguous i8)

    for (int kt = 0; kt < K_DIM / BK; kt++) {
        const int k0 = kt * BK;
        __syncthreads();  // previous iter's ds_reads done before overwrite
        #pragma unroll
        for (int i = 0; i < 2; i++) {
            int c = cbase + i * 256;
            int row = c >> 2, koff = (c & 3) * 16;
            async_copy16(Abase + (size_t)row * K_DIM + k0 + koff,
                         As + i * 4096 + wave * 1024);
        }
        #pragma unroll
        for (int i = 0; i < 2; i++) {
            int c = cbase + i * 256;
            int row = c >> 2, koff = (c & 3) * 16;
            async_copy16(Bbase + (size_t)row * K_DIM + k0 + koff,
                         Bs + i * 4096 + wave * 1024);
        }
        __syncthreads();  // compiler drains vmcnt(0) before s_barrier

        v4i a[4], b[4];
        #pragma unroll
        for (int mi = 0; mi < 4; mi++)
            a[mi] = *(const v4i*)(As + (wm + mi * 16 + fr) * BK + kq);
        #pragma unroll
        for (int ni = 0; ni < 4; ni++)
            b[ni] = *(const v4i*)(Bs + (wn + ni * 16 + fr) * BK + kq);
        #pragma unroll
        for (int mi = 0; mi < 4; mi++) {
            #pragma unroll
            for (int ni = 0; ni < 4; ni++) {
                acc[mi][ni] = __builtin_amdgcn_mfma_i32_16x16x64_i8(
                    a[mi], b[ni], acc[mi][ni], 0, 0, 0);
            }
        }
    }

    // Epilogue: C/D layout col=lane&15, row=(lane>>4)*4+reg (dtype-indep).
    float mw = (float)fmax((*macc) * inv_cnt, (double)QEPS);
    const int col0 = bn + wn + (lane & 15);
    const int rbase = bm + wm + (lane >> 4) * 4;
    #pragma unroll
    for (int mi = 0; mi < 4; mi++) {
        #pragma unroll
        for (int r = 0; r < 4; r++) {
            int row = rbase + mi * 16 + r;
            float rs = rowscale[row] * mw;
            float* crow = C + (size_t)row * N_DIM;
            #pragma unroll
            for (int ni = 0; ni < 4; ni++) {
                crow[col0 + ni * 16] = (float)acc[mi][ni][r] * rs;
            }
        }
    }
}

// ---------------- launch ----------------
extern "C" void kernel_launch(void* const* d_in, const int* in_sizes, int n_in,
                              void* d_out, int out_size, void* d_ws,
                              size_t ws_size, hipStream_t stream) {
    const float* x = (const float*)d_in[0];
    const float* w = (const float*)d_in[1];
    float* out = (float*)d_out;

    const size_t QX_BYTES = (size_t)M_DIM * K_DIM;        // 33554432
    const size_t TW_BYTES = (size_t)N_DIM * K_DIM;        // 67108864
    int8_t* qx = (int8_t*)d_ws;
    int8_t* tw = (int8_t*)d_ws + QX_BYTES;
    float* rowscale = (float*)((char*)d_ws + QX_BYTES + TW_BYTES);
    double* macc = (double*)((char*)d_ws + QX_BYTES + TW_BYTES +
                             (size_t)M_DIM * sizeof(float));

    const double inv_cnt = 1.0 / (double)((size_t)N_DIM * K_DIM);

    hipMemsetAsync(macc, 0, sizeof(double), stream);
    wabs_sum<<<1024, 256, 0, stream>>>(w, macc, (N_DIM * K_DIM) / 4);
    wquant<<<2048, 256, 0, stream>>>(w, tw, macc, inv_cnt, (N_DIM * K_DIM) / 4);
    xquant<<<M_DIM, 256, 0, stream>>>(x, qx, rowscale);
    dim3 grid(N_DIM / BN, M_DIM / BM);
    gemm_i8<<<grid, 256, 0, stream>>>(qx, tw, rowscale, macc, inv_cnt, out);
}